// Round 2
// baseline (26531.006 us; speedup 1.0000x reference)
//
#include <hip/hip_runtime.h>

#define T_STEPS 1024
#define BATCH   128
#define IDIM    256
#define HDIM    512
#define BH      (BATCH * HDIM)      // 65536
#define TBH     (T_STEPS * BH)      // 67108864
#define RING_SLOTS 2                // skew within a group is provably <= 1 step

using short8  = __attribute__((ext_vector_type(8))) short;
using floatx4 = __attribute__((ext_vector_type(4))) float;

// ---------- cheap truncation hi/lo split (error ~2^-16 rel, fine vs 2e-2) ----------
__device__ __forceinline__ void split_trunc(float f, unsigned short& hi, unsigned short& lo) {
  unsigned u = __builtin_bit_cast(unsigned, f);
  hi = (unsigned short)(u >> 16);
  float r = f - __builtin_bit_cast(float, u & 0xFFFF0000u);
  lo = (unsigned short)(__builtin_bit_cast(unsigned, r) >> 16);
}
__device__ __forceinline__ float fast_tanh(float x) {
  float e = __expf(2.0f * x);
  return 1.0f - 2.0f * __builtin_amdgcn_rcpf(e + 1.0f);
}

// Convert 16 consecutive fp32 -> bf16 hi/lo planes, vector-store to LDS.
__device__ __forceinline__ void stage16(const float4* __restrict__ p,
                                        unsigned short* dhi, unsigned short* dlo) {
  short8 h0{}, h1{}, l0{}, l1{};
#pragma unroll
  for (int v = 0; v < 4; v++) {
    float4 fv = p[v];
    float fs[4] = {fv.x, fv.y, fv.z, fv.w};
#pragma unroll
    for (int e = 0; e < 4; e++) {
      int idx = v * 4 + e;
      unsigned short hh, ll;
      split_trunc(fs[e], hh, ll);
      if (idx < 8) { h0[idx] = (short)hh; l0[idx] = (short)ll; }
      else         { h1[idx - 8] = (short)hh; l1[idx - 8] = (short)ll; }
    }
  }
  *(short8*)(dhi)     = h0;
  *(short8*)(dhi + 8) = h1;
  *(short8*)(dlo)     = l0;
  *(short8*)(dlo + 8) = l1;
}

// ================= Kernel A: xw = x @ Wi^T  (written into d_out[0..TBH)) ==========
__global__ __launch_bounds__(256, 2) void xw_gemm(const float* __restrict__ x,
                                                  const float* __restrict__ Wi,
                                                  float* __restrict__ out) {
  __shared__ unsigned short Ahi[128 * 40], Alo[128 * 40];
  __shared__ unsigned short Bhi[128 * 40], Blo[128 * 40];
  const int bx   = blockIdx.x;
  const int m0   = (bx >> 2) * 128;
  const int n0   = (bx & 3) * 128;
  const int tid  = threadIdx.x;
  const int lane = tid & 63;
  const int wave = tid >> 6;
  const int q    = lane >> 4;
  const int ml   = lane & 15;
  const int wm   = (wave >> 1) * 64;
  const int wn   = (wave & 1) * 64;
  const int srow = tid & 127;
  const int skh  = tid >> 7;

  floatx4 acc[4][4];
#pragma unroll
  for (int i = 0; i < 4; i++)
#pragma unroll
    for (int j = 0; j < 4; j++)
      acc[i][j] = floatx4{0.f, 0.f, 0.f, 0.f};

  for (int kb = 0; kb < 8; kb++) {
    stage16((const float4*)(x  + (size_t)(m0 + srow) * IDIM + kb * 32 + skh * 16),
            &Ahi[srow * 40 + skh * 16], &Alo[srow * 40 + skh * 16]);
    stage16((const float4*)(Wi + (size_t)(n0 + srow) * IDIM + kb * 32 + skh * 16),
            &Bhi[srow * 40 + skh * 16], &Blo[srow * 40 + skh * 16]);
    __syncthreads();

    short8 ah[4], al[4], bh[4], bl[4];
#pragma unroll
    for (int f = 0; f < 4; f++) {
      ah[f] = *(const short8*)&Ahi[(wm + f * 16 + ml) * 40 + q * 8];
      al[f] = *(const short8*)&Alo[(wm + f * 16 + ml) * 40 + q * 8];
      bh[f] = *(const short8*)&Bhi[(wn + f * 16 + ml) * 40 + q * 8];
      bl[f] = *(const short8*)&Blo[(wn + f * 16 + ml) * 40 + q * 8];
    }
#pragma unroll
    for (int mf = 0; mf < 4; mf++)
#pragma unroll
      for (int nf = 0; nf < 4; nf++) {
        acc[mf][nf] = __builtin_amdgcn_mfma_f32_16x16x32_bf16(ah[mf], bh[nf], acc[mf][nf], 0, 0, 0);
        acc[mf][nf] = __builtin_amdgcn_mfma_f32_16x16x32_bf16(ah[mf], bl[nf], acc[mf][nf], 0, 0, 0);
        acc[mf][nf] = __builtin_amdgcn_mfma_f32_16x16x32_bf16(al[mf], bh[nf], acc[mf][nf], 0, 0, 0);
      }
    __syncthreads();
  }

#pragma unroll
  for (int mf = 0; mf < 4; mf++)
#pragma unroll
    for (int nf = 0; nf < 4; nf++)
#pragma unroll
      for (int r = 0; r < 4; r++)
        out[(size_t)(m0 + wm + mf * 16 + q * 4 + r) * HDIM + (n0 + wn + nf * 16 + ml)] =
            acc[mf][nf][r];
}

// ================= Kernel B: recurrence, flagless self-stamped exchange ==========
// 32 blocks = 8 batch-groups (16 rows) x 4 j-groups (128 cols), 1024 threads each.
// 2-way K-split across wave pairs (Wh frags 64 VGPR/lane). h exchanged via a
// 2-slot ring of u64 words: (lo16<<16|t)<<32 | (hi16<<16|t). Relaxed agent-scope
// atomics bypass the non-coherent per-XCD L2 -> single LLC round-trip, no flags,
// no buffer_inv/wbl2. Readers poll the data words' stamps directly.
// LDS h planes are stored in MFMA A-fragment order -> all ds ops are b128,
// lane-contiguous, conflict-free.
__global__ __launch_bounds__(1024) void rnn_scan(const float* __restrict__ Wh,
                                                 float* out,
                                                 unsigned long long* __restrict__ ring) {
  __shared__ unsigned short Hhi[2][8192], Hlo[2][8192];  // [buf][frag-major 16x512]
  __shared__ floatx4 red[8 * 64];                        // kw1 partial sums

  const int tid  = threadIdx.x;
  const int lane = tid & 63;
  const int wave = tid >> 6;
  const int q    = lane >> 4;
  const int ml   = lane & 15;
  const int bg   = blockIdx.x & 7;
  const int jg   = blockIdx.x >> 3;
  const int cg   = wave >> 1;          // col-group (8 x 16 cols)
  const int kw   = wave & 1;           // K-half (0: k<256, 1: k>=256)
  const int col  = jg * 128 + cg * 16 + ml;
  const int rowq = q * 4;              // local row base; global row = bg*16+rowq+r

  // Task decomposition: 1024 threads = 4 peers x 16 rows x 16 col-groups-of-8.
  const int tp = tid >> 8;             // peer j-group
  const int tg = (tid >> 4) & 15;      // col-group-of-8 within peer slice
  const int tr = tid & 15;             // row
  const int tk = tp * 128 + tg * 8;    // k of first element
  const int t_lds  = (((tk >> 5) * 4 + ((tk >> 3) & 3)) * 16 + tr) * 8;  // halfword idx
  const int t_elem = tr * 128 + tg * 8;

  // ---- Wh fragments in registers: 8 chunks of K=32 (this wave's K-half) ----
  short8 wh_hi[8], wh_lo[8];
#pragma unroll
  for (int i = 0; i < 8; i++) {
    const int c = kw * 8 + i;
    const float4* p = (const float4*)(Wh + (size_t)col * HDIM + c * 32 + q * 8);
    float4 u = p[0], v = p[1];
    float fs[8] = {u.x, u.y, u.z, u.w, v.x, v.y, v.z, v.w};
    short8 h{}, l{};
#pragma unroll
    for (int e = 0; e < 8; e++) {
      unsigned short hh, ll;
      split_trunc(fs[e], hh, ll);
      h[e] = (short)hh; l[e] = (short)ll;
    }
    wh_hi[i] = h; wh_lo[i] = l;
  }

  for (int t = 0; t < T_STEPS; t++) {
    const int slot = t & (RING_SLOTS - 1);

    // Issue xw loads early (own slice of out[t]; consumed at epilogue after MFMA).
    float xwv[4];
    if (kw == 0) {
#pragma unroll
      for (int r = 0; r < 4; r++)
        xwv[r] = out[(size_t)t * BH + (size_t)(bg * 16 + rowq + r) * HDIM + col];
    }

    floatx4 acc = floatx4{0.f, 0.f, 0.f, 0.f};
    if (t > 0) {
      const int buf = (t - 1) & 1;
#pragma unroll
      for (int i = 0; i < 8; i++) {
        const int c = kw * 8 + i;
        short8 ahi = *(const short8*)&Hhi[buf][((c * 4 + q) * 16 + ml) * 8];
        short8 alo = *(const short8*)&Hlo[buf][((c * 4 + q) * 16 + ml) * 8];
        acc = __builtin_amdgcn_mfma_f32_16x16x32_bf16(ahi, wh_hi[i], acc, 0, 0, 0);
        acc = __builtin_amdgcn_mfma_f32_16x16x32_bf16(ahi, wh_lo[i], acc, 0, 0, 0);
        acc = __builtin_amdgcn_mfma_f32_16x16x32_bf16(alo, wh_hi[i], acc, 0, 0, 0);
      }
      // combine K-halves
      if (kw == 1) red[cg * 64 + lane] = acc;
      __syncthreads();
      if (kw == 0) {
        floatx4 p = red[cg * 64 + lane];
#pragma unroll
        for (int r = 0; r < 4; r++) acc[r] += p[r];
      }
    }

    // Epilogue: h = tanh(xw + hWh^T); store fp32 out; publish stamped bf16 words.
    if (kw == 0) {
#pragma unroll
      for (int r = 0; r < 4; r++) {
        float h = fast_tanh(acc[r] + xwv[r]);
        size_t oidx = (size_t)t * BH + (size_t)(bg * 16 + rowq + r) * HDIM + col;
        out[oidx] = h;
        if (t == T_STEPS - 1)
          out[(size_t)TBH + (size_t)(bg * 16 + rowq + r) * HDIM + col] = h;
        if (t < T_STEPS - 1) {
          unsigned short hh, ll;
          split_trunc(h, hh, ll);
          unsigned w0 = ((unsigned)hh << 16) | (unsigned)t;
          unsigned w1 = ((unsigned)ll << 16) | (unsigned)t;
          unsigned long long wrd = ((unsigned long long)w1 << 32) | w0;
          int elem = (rowq + r) * 128 + cg * 16 + ml;
          __hip_atomic_store(&ring[(size_t)((slot * 8 + bg) * 4 + jg) * 2048 + elem],
                             wrd, __ATOMIC_RELAXED, __HIP_MEMORY_SCOPE_AGENT);
        }
      }
    }

    if (t < T_STEPS - 1) {
      // Poll this thread's fragment task (8 u64 = one short8 hi + one short8 lo).
      unsigned long long* tpp =
          &ring[(size_t)((slot * 8 + bg) * 4 + tp) * 2048 + t_elem];
      unsigned long long v[8];
      const unsigned stamp = (unsigned)t;
      for (;;) {
        bool ok = true;
#pragma unroll
        for (int j = 0; j < 8; j++)
          v[j] = __hip_atomic_load(&tpp[j], __ATOMIC_RELAXED, __HIP_MEMORY_SCOPE_AGENT);
#pragma unroll
        for (int j = 0; j < 8; j++)
          ok &= (((unsigned)v[j] & 0xFFFFu) == stamp) &&
                (((unsigned)(v[j] >> 32) & 0xFFFFu) == stamp);
        if (ok) break;
        __builtin_amdgcn_s_sleep(1);
      }
      short8 h, l;
#pragma unroll
      for (int j = 0; j < 8; j++) {
        h[j] = (short)((unsigned)v[j] >> 16);
        l[j] = (short)(v[j] >> 48);
      }
      const int buf = t & 1;
      *(short8*)&Hhi[buf][t_lds] = h;
      *(short8*)&Hlo[buf][t_lds] = l;
      __syncthreads();
    }
  }
}

extern "C" void kernel_launch(void* const* d_in, const int* in_sizes, int n_in,
                              void* d_out, int out_size, void* d_ws, size_t ws_size,
                              hipStream_t stream) {
  const float* x  = (const float*)d_in[0];   // [T,B,I]
  const float* Wi = (const float*)d_in[1];   // [H,I]
  const float* Wh = (const float*)d_in[2];   // [H,H]
  float* out      = (float*)d_out;           // [T,B,H] ++ [B,H]
  unsigned long long* ring = (unsigned long long*)d_ws;

  // Re-poison ring every launch: stamp field becomes 0xAAAA (never == t).
  hipMemsetAsync(d_ws, 0xAA, (size_t)RING_SLOTS * 8 * 4 * 2048 * 8, stream);

  xw_gemm<<<dim3((131072 / 128) * (HDIM / 128)), dim3(256), 0, stream>>>(x, Wi, out);
  rnn_scan<<<dim3(32), dim3(1024), 0, stream>>>(Wh, out, ring);
}